// Round 3
// baseline (491.346 us; speedup 1.0000x reference)
//
#include <hip/hip_runtime.h>
#include <cstdint>
#include <cstddef>

#define NROWS 32768
#define DDIM  64
#define KDIM  8192
#define BR 128            // rows per block tile
#define BK 128            // codewords per block tile
#define DPH 32            // D per phase (2 phases)

typedef float v2f __attribute__((ext_vector_type(2)));

// ---- prep: wt[k][d] = w[d][k] (for gather); wsq[k] = sum_d w[d][k]^2 ----
__global__ void vq_prep(const float* __restrict__ w,
                        float* __restrict__ wt,
                        float* __restrict__ wsq) {
    int k = blockIdx.x * blockDim.x + threadIdx.x;
    if (k >= KDIM) return;
    float s = 0.f;
#pragma unroll
    for (int d = 0; d < DDIM; ++d) {
        float v = w[(size_t)d * KDIM + k];   // coalesced across lanes
        wt[(size_t)k * DDIM + d] = v;
        s = fmaf(v, v, s);
    }
    wsq[k] = s;
}

__global__ void vq_init(unsigned long long* __restrict__ keys) {
    int i = blockIdx.x * blockDim.x + threadIdx.x;
    if (i < NROWS) keys[i] = ~0ull;
}

// ---- fused GEMM + argmin, D split into two 32-wide phases (32 KiB LDS) ----
// Block tile 128x128, 4 waves in 2x2 (wave tile 64x64), lane tile 8x8.
__global__ void __launch_bounds__(256, 4)
vq_gemm(const float* __restrict__ x,
        const float* __restrict__ w,
        const float* __restrict__ wsq,
        unsigned long long* __restrict__ keys) {
    __shared__ float xT[DPH][BR];   // 16 KiB, transposed x half-tile
    __shared__ float wl[DPH][BK];   // 16 KiB

    const int kblk  = blockIdx.x & (KDIM / BK - 1);   // fast dim: k-blocks
    const int rbase = (blockIdx.x >> 6) * BR;
    const int kbase = kblk * BK;
    const int t     = threadIdx.x;

    const int wave = t >> 6, lane = t & 63;
    const int rg = lane >> 3, cg = lane & 7;
    const int xoff = (wave >> 1) * 64 + rg * 8;   // row offset in block
    const int coff = (wave & 1) * 64 + cg * 8;    // col offset in block

    v2f acc[8][4];
#pragma unroll
    for (int i = 0; i < 8; ++i)
#pragma unroll
        for (int j = 0; j < 4; ++j) acc[i][j] = (v2f)(0.f);

#pragma unroll
    for (int p = 0; p < 2; ++p) {
        // ---- stage x transposed (scalar writes, 2-way/bcast -> conflict-free)
        {
            const int row  = t & 127;
            const int dgrp = t >> 7;   // 0/1
#pragma unroll
            for (int it = 0; it < 4; ++it) {
                const int dl = (dgrp + it * 2) * 4;   // 0,8,16,24 (+4)
                float4 v = *(const float4*)&x[(size_t)(rbase + row) * DDIM + p * DPH + dl];
                xT[dl + 0][row] = v.x;
                xT[dl + 1][row] = v.y;
                xT[dl + 2][row] = v.z;
                xT[dl + 3][row] = v.w;
            }
        }
        // ---- stage w half-tile: coalesced float4 reads, linear b128 writes
        {
#pragma unroll
            for (int it = 0; it < 4; ++it) {
                const int o4 = t + it * 256;          // float4 idx in [32][32]
                const int dl = o4 >> 5;
                const int c4 = (o4 & 31) << 2;
                float4 v = *(const float4*)&w[(size_t)(p * DPH + dl) * KDIM + kbase + c4];
                *(float4*)&wl[dl][c4] = v;
            }
        }
        __syncthreads();

#pragma unroll 4
        for (int d = 0; d < DPH; ++d) {
            float4 xa = *(const float4*)&xT[d][xoff];
            float4 xb = *(const float4*)&xT[d][xoff + 4];
            float4 wa = *(const float4*)&wl[d][coff];
            float4 wb = *(const float4*)&wl[d][coff + 4];
            v2f wv0 = {wa.x, wa.y}, wv1 = {wa.z, wa.w};
            v2f wv2 = {wb.x, wb.y}, wv3 = {wb.z, wb.w};
            float xr[8] = {xa.x, xa.y, xa.z, xa.w, xb.x, xb.y, xb.z, xb.w};
#pragma unroll
            for (int i = 0; i < 8; ++i) {
                v2f xs = {xr[i], xr[i]};
                acc[i][0] = __builtin_elementwise_fma(xs, wv0, acc[i][0]);
                acc[i][1] = __builtin_elementwise_fma(xs, wv1, acc[i][1]);
                acc[i][2] = __builtin_elementwise_fma(xs, wv2, acc[i][2]);
                acc[i][3] = __builtin_elementwise_fma(xs, wv3, acc[i][3]);
            }
        }
        __syncthreads();   // protect LDS before next phase's staging
    }

    // ---- epilogue: score = wsq[k] - 2*dot (|x|^2 constant per row, dropped)
    const int kc = kbase + coff;
    float4 qa = *(const float4*)&wsq[kc];
    float4 qb = *(const float4*)&wsq[kc + 4];
    v2f q2[4] = {{qa.x, qa.y}, {qa.z, qa.w}, {qb.x, qb.y}, {qb.z, qb.w}};
    const v2f neg2 = {-2.f, -2.f};

#pragma unroll
    for (int i = 0; i < 8; ++i) {
        float sc[8];
#pragma unroll
        for (int jj = 0; jj < 4; ++jj) {
            v2f s2 = __builtin_elementwise_fma(neg2, acc[i][jj], q2[jj]);
            sc[2 * jj]     = s2.x;
            sc[2 * jj + 1] = s2.y;
        }
        float best = sc[0];
        int   bj   = 0;
#pragma unroll
        for (int j = 1; j < 8; ++j)
            if (sc[j] < best) { best = sc[j]; bj = j; }   // strict < => lowest k
        uint32_t u = __float_as_uint(best);
        u = (u & 0x80000000u) ? ~u : (u | 0x80000000u);   // monotonic fp32->u32
        unsigned long long key =
            ((unsigned long long)u << 32) | (unsigned)(kc + bj);
        unsigned long long o;
        o = __shfl_xor(key, 1); key = (o < key) ? o : key;
        o = __shfl_xor(key, 2); key = (o < key) ? o : key;
        o = __shfl_xor(key, 4); key = (o < key) ? o : key;
        if (cg == 0) atomicMin(&keys[rbase + xoff + i], key);
    }
}

// ---- gather: out[row][d] = wt[bestk[row]][d] ----
__global__ void vq_gather(const unsigned long long* __restrict__ keys,
                          const float* __restrict__ wt,
                          float* __restrict__ out) {
    int t = blockIdx.x * blockDim.x + threadIdx.x;
    if (t >= NROWS * DDIM) return;
    int row = t >> 6;
    int d   = t & 63;
    int k   = (int)(keys[row] & 0xFFFFFFFFull);
    out[t] = wt[(size_t)k * DDIM + d];
}

extern "C" void kernel_launch(void* const* d_in, const int* in_sizes, int n_in,
                              void* d_out, int out_size, void* d_ws, size_t ws_size,
                              hipStream_t stream) {
    const float* x = (const float*)d_in[0];   // [32768, 64]
    const float* w = (const float*)d_in[1];   // [64, 8192]
    float* out = (float*)d_out;               // [32768, 64]

    char* ws = (char*)d_ws;
    float* wt  = (float*)ws;                                   // 2 MiB
    float* wsq = (float*)(ws + (size_t)KDIM * DDIM * 4);       // 32 KiB
    unsigned long long* keys =
        (unsigned long long*)(ws + (size_t)KDIM * DDIM * 4 + KDIM * 4); // 256 KiB

    vq_prep<<<KDIM / 256, 256, 0, stream>>>(w, wt, wsq);
    vq_init<<<NROWS / 256, 256, 0, stream>>>(keys);
    vq_gemm<<<(NROWS / BR) * (KDIM / BK), 256, 0, stream>>>(x, w, wsq, keys);
    vq_gather<<<(NROWS * DDIM + 255) / 256, 256, 0, stream>>>(keys, wt, out);
}